// Round 4
// baseline (185.997 us; speedup 1.0000x reference)
//
#include <hip/hip_runtime.h>

// MRPCEN: multi-rate PCEN.
//   x: (B=16, F=128, T=4096) f32; alpha_log/delta_log/r_log: (F,) f32
//   out: (B, 4, F, T) f32
// m[b,f,0]=x[b,f,0]; m[t]=(1-s)m[t-1]+s x[t]  (4 s-values, compile-time consts)
// out = (x*(EPS+m)^(-alpha) + delta)^r - delta^r
//
// R4 = R3 with compile fix: __builtin_nontemporal_store needs a clang
// ext_vector_type pointer, not HIP's float4 class. 512 threads/block,
// 8 contiguous elements/thread (two float4 loads), nontemporal float4 stores
// for the write-once 134 MB output. Decoupled scan: local 8-step recurrence
// (zero init) -> wave Hillis-Steele scan with decay (1-s)^8 -> cross-wave
// combine via LDS, ONE barrier (all 4 s batched). Initial condition folded by
// seeding carry with x[0].
//
// NOTE: no <math.h> include — glibc's __MATHCALL declares __exp2f etc. and
// collides with HIP device intrinsics. Use __builtin_amdgcn_* directly.

#define EPS_C 1e-5f

typedef float vfloat4 __attribute__((ext_vector_type(4)));

__device__ __forceinline__ float fexp2(float v) { return __builtin_amdgcn_exp2f(v); }
__device__ __forceinline__ float flog2(float v) { return __builtin_amdgcn_logf(v); }
__device__ __forceinline__ float fpow(float a, float b) { return fexp2(b * flog2(a)); }
__device__ __forceinline__ float fexp(float v) { return fexp2(v * 1.44269504f); }

__global__ __launch_bounds__(512)
void pcen_kernel(const float* __restrict__ x,
                 const float* __restrict__ alpha_log,
                 const float* __restrict__ delta_log,
                 const float* __restrict__ r_log,
                 float* __restrict__ out)
{
    const int row  = blockIdx.x;          // b*128 + f
    const int f    = row & 127;
    const int b    = row >> 7;
    const int tid  = threadIdx.x;         // 0..511
    const int lane = tid & 63;
    const int w    = tid >> 6;            // wave id 0..7

    __shared__ float wq[4][8];            // per-s, per-wave inclusive scan tails
    __shared__ float sh_x0;

    // Per-F parameters early (scalar loads overlap the vector loads)
    const float al = alpha_log[f], dl = delta_log[f], rl = r_log[f];

    const vfloat4* __restrict__ xrow4 = (const vfloat4*)(x + (size_t)row * 4096);
    vfloat4 xa = xrow4[2 * tid];          // elements 8t..8t+3
    vfloat4 xb = xrow4[2 * tid + 1];      // elements 8t+4..8t+7
    if (tid == 0) sh_x0 = xa.x;

    // s-values from module constants (const-folded by the compiler)
    const float Tv[4] = {0.015f, 0.06f, 0.25f, 1.0f};
    float s_arr[4], omn_arr[4];
#pragma unroll
    for (int i = 0; i < 4; ++i) {
        float t  = Tv[i] * 86.1328125f;   // 44100/512
        float t2 = t * t;
        float s  = (__builtin_sqrtf(1.0f + 4.0f * t2) - 1.0f) / (2.0f * t2);
        s_arr[i]   = s;
        omn_arr[i] = 1.0f - s;
    }

    // Phase 1: per-s local 8-step recurrence + wave scan (no barrier yet)
    float qxv[4];
#pragma unroll
    for (int i = 0; i < 4; ++i) {
        const float s = s_arr[i], omn = omn_arr[i];
        float p = s * xa.x;
        p = fmaf(omn, p, s * xa.y);
        p = fmaf(omn, p, s * xa.z);
        p = fmaf(omn, p, s * xa.w);
        p = fmaf(omn, p, s * xb.x);
        p = fmaf(omn, p, s * xb.y);
        p = fmaf(omn, p, s * xb.z);
        p = fmaf(omn, p, s * xb.w);
        // wave-level inclusive scan of segment sums, segment decay omn^8
        float q = p;
        float c = omn * omn; c = c * c; c = c * c;   // omn^8
#pragma unroll
        for (int k = 0; k < 6; ++k) {
            int d = 1 << k;
            float tsh = __shfl_up(q, d);
            if (lane >= d) q = fmaf(c, tsh, q);
            c = c * c;
        }
        float qx = __shfl_up(q, 1);       // within-wave exclusive
        if (lane == 0) qx = 0.0f;
        qxv[i] = qx;
        if (lane == 63) wq[i][w] = q;
    }
    __syncthreads();                       // the only barrier

    const float nalpha  = -fexp(al);
    const float delta   =  fexp(dl);
    const float r       =  fexp(rl);
    const float delta_r =  fexp(r * dl);  // delta^r = exp(r*log(delta))

    const float x0 = sh_x0;
    vfloat4* __restrict__ out4 = (vfloat4*)out;

#pragma unroll
    for (int i = 0; i < 4; ++i) {
        const float s = s_arr[i], omn = omn_arr[i];
        const float l2omn = flog2(omn);
        const float Dw = fexp2(512.0f * l2omn);      // omn^512 (wave decay)
        // carry entering this wave; seed with M(-1)=x0 so m[0]=x[0] exactly
        float Q = x0;
        for (int v = 0; v < w; ++v) Q = fmaf(Dw, Q, wq[i][v]);
        // carry entering this thread's 8-element segment
        const float dl8 = fexp2((float)(8 * lane) * l2omn); // omn^(8*lane)
        const float E = fmaf(dl8, Q, qxv[i]);
        // replay recurrence from true carry
        float m0 = fmaf(omn, E,  s * xa.x);
        float m1 = fmaf(omn, m0, s * xa.y);
        float m2 = fmaf(omn, m1, s * xa.z);
        float m3 = fmaf(omn, m2, s * xa.w);
        float m4 = fmaf(omn, m3, s * xb.x);
        float m5 = fmaf(omn, m4, s * xb.y);
        float m6 = fmaf(omn, m5, s * xb.z);
        float m7 = fmaf(omn, m6, s * xb.w);
        // pcen = (x*(EPS+m)^(-alpha) + delta)^r - delta^r
        vfloat4 oa, ob;
        oa.x = fpow(fmaf(xa.x, fpow(EPS_C + m0, nalpha), delta), r) - delta_r;
        oa.y = fpow(fmaf(xa.y, fpow(EPS_C + m1, nalpha), delta), r) - delta_r;
        oa.z = fpow(fmaf(xa.z, fpow(EPS_C + m2, nalpha), delta), r) - delta_r;
        oa.w = fpow(fmaf(xa.w, fpow(EPS_C + m3, nalpha), delta), r) - delta_r;
        ob.x = fpow(fmaf(xb.x, fpow(EPS_C + m4, nalpha), delta), r) - delta_r;
        ob.y = fpow(fmaf(xb.y, fpow(EPS_C + m5, nalpha), delta), r) - delta_r;
        ob.z = fpow(fmaf(xb.z, fpow(EPS_C + m6, nalpha), delta), r) - delta_r;
        ob.w = fpow(fmaf(xb.w, fpow(EPS_C + m7, nalpha), delta), r) - delta_r;

        const size_t obase4 = ((size_t)((b * 4 + i) * 128 + f)) * 1024; // /4
        __builtin_nontemporal_store(oa, &out4[obase4 + 2 * tid]);
        __builtin_nontemporal_store(ob, &out4[obase4 + 2 * tid + 1]);
    }
}

extern "C" void kernel_launch(void* const* d_in, const int* in_sizes, int n_in,
                              void* d_out, int out_size, void* d_ws, size_t ws_size,
                              hipStream_t stream) {
    const float* x  = (const float*)d_in[0];
    const float* al = (const float*)d_in[1];
    const float* dl = (const float*)d_in[2];
    const float* rl = (const float*)d_in[3];
    float* out = (float*)d_out;
    const int rows = in_sizes[0] / 4096;   // B*F = 2048
    pcen_kernel<<<rows, 512, 0, stream>>>(x, al, dl, rl, out);
}

// Round 5
// 166.621 us; speedup vs baseline: 1.1163x; 1.1163x over previous
//
#include <hip/hip_runtime.h>

// MRPCEN: multi-rate PCEN.
//   x: (B=16, F=128, T=4096) f32; alpha_log/delta_log/r_log: (F,) f32
//   out: (B, 4, F, T) f32
// m[b,f,0]=x[b,f,0]; m[t]=(1-s)m[t-1]+s x[t]  (4 s-values, compile-time consts)
// out = (x*(EPS+m)^(-alpha) + delta)^r - delta^r
//
// R5 = R4 with nontemporal stores REVERTED to plain vector stores
// (single-variable experiment: R4's nt stores + 512-thread switch together
// regressed 164->186 µs; fills hit 6.5 TB/s with normal stores, so the
// L2 write-back path appears to be the fast streaming-write path).
// 512 threads/block, 8 contiguous elements/thread (two float4 loads).
// Decoupled scan: local 8-step recurrence (zero init) -> wave Hillis-Steele
// scan with decay (1-s)^8 -> cross-wave combine via LDS, ONE barrier (all 4 s
// batched). Initial condition folded by seeding carry with x[0].
//
// NOTE: no <math.h> include — glibc's __MATHCALL declares __exp2f etc. and
// collides with HIP device intrinsics. Use __builtin_amdgcn_* directly.

#define EPS_C 1e-5f

typedef float vfloat4 __attribute__((ext_vector_type(4)));

__device__ __forceinline__ float fexp2(float v) { return __builtin_amdgcn_exp2f(v); }
__device__ __forceinline__ float flog2(float v) { return __builtin_amdgcn_logf(v); }
__device__ __forceinline__ float fpow(float a, float b) { return fexp2(b * flog2(a)); }
__device__ __forceinline__ float fexp(float v) { return fexp2(v * 1.44269504f); }

__global__ __launch_bounds__(512)
void pcen_kernel(const float* __restrict__ x,
                 const float* __restrict__ alpha_log,
                 const float* __restrict__ delta_log,
                 const float* __restrict__ r_log,
                 float* __restrict__ out)
{
    const int row  = blockIdx.x;          // b*128 + f
    const int f    = row & 127;
    const int b    = row >> 7;
    const int tid  = threadIdx.x;         // 0..511
    const int lane = tid & 63;
    const int w    = tid >> 6;            // wave id 0..7

    __shared__ float wq[4][8];            // per-s, per-wave inclusive scan tails
    __shared__ float sh_x0;

    // Per-F parameters early (scalar loads overlap the vector loads)
    const float al = alpha_log[f], dl = delta_log[f], rl = r_log[f];

    const vfloat4* __restrict__ xrow4 = (const vfloat4*)(x + (size_t)row * 4096);
    vfloat4 xa = xrow4[2 * tid];          // elements 8t..8t+3
    vfloat4 xb = xrow4[2 * tid + 1];      // elements 8t+4..8t+7
    if (tid == 0) sh_x0 = xa.x;

    // s-values from module constants (const-folded by the compiler)
    const float Tv[4] = {0.015f, 0.06f, 0.25f, 1.0f};
    float s_arr[4], omn_arr[4];
#pragma unroll
    for (int i = 0; i < 4; ++i) {
        float t  = Tv[i] * 86.1328125f;   // 44100/512
        float t2 = t * t;
        float s  = (__builtin_sqrtf(1.0f + 4.0f * t2) - 1.0f) / (2.0f * t2);
        s_arr[i]   = s;
        omn_arr[i] = 1.0f - s;
    }

    // Phase 1: per-s local 8-step recurrence + wave scan (no barrier yet)
    float qxv[4];
#pragma unroll
    for (int i = 0; i < 4; ++i) {
        const float s = s_arr[i], omn = omn_arr[i];
        float p = s * xa.x;
        p = fmaf(omn, p, s * xa.y);
        p = fmaf(omn, p, s * xa.z);
        p = fmaf(omn, p, s * xa.w);
        p = fmaf(omn, p, s * xb.x);
        p = fmaf(omn, p, s * xb.y);
        p = fmaf(omn, p, s * xb.z);
        p = fmaf(omn, p, s * xb.w);
        // wave-level inclusive scan of segment sums, segment decay omn^8
        float q = p;
        float c = omn * omn; c = c * c; c = c * c;   // omn^8
#pragma unroll
        for (int k = 0; k < 6; ++k) {
            int d = 1 << k;
            float tsh = __shfl_up(q, d);
            if (lane >= d) q = fmaf(c, tsh, q);
            c = c * c;
        }
        float qx = __shfl_up(q, 1);       // within-wave exclusive
        if (lane == 0) qx = 0.0f;
        qxv[i] = qx;
        if (lane == 63) wq[i][w] = q;
    }
    __syncthreads();                       // the only barrier

    const float nalpha  = -fexp(al);
    const float delta   =  fexp(dl);
    const float r       =  fexp(rl);
    const float delta_r =  fexp(r * dl);  // delta^r = exp(r*log(delta))

    const float x0 = sh_x0;
    vfloat4* __restrict__ out4 = (vfloat4*)out;

#pragma unroll
    for (int i = 0; i < 4; ++i) {
        const float s = s_arr[i], omn = omn_arr[i];
        const float l2omn = flog2(omn);
        const float Dw = fexp2(512.0f * l2omn);      // omn^512 (wave decay)
        // carry entering this wave; seed with M(-1)=x0 so m[0]=x[0] exactly
        float Q = x0;
        for (int v = 0; v < w; ++v) Q = fmaf(Dw, Q, wq[i][v]);
        // carry entering this thread's 8-element segment
        const float dl8 = fexp2((float)(8 * lane) * l2omn); // omn^(8*lane)
        const float E = fmaf(dl8, Q, qxv[i]);
        // replay recurrence from true carry
        float m0 = fmaf(omn, E,  s * xa.x);
        float m1 = fmaf(omn, m0, s * xa.y);
        float m2 = fmaf(omn, m1, s * xa.z);
        float m3 = fmaf(omn, m2, s * xa.w);
        float m4 = fmaf(omn, m3, s * xb.x);
        float m5 = fmaf(omn, m4, s * xb.y);
        float m6 = fmaf(omn, m5, s * xb.z);
        float m7 = fmaf(omn, m6, s * xb.w);
        // pcen = (x*(EPS+m)^(-alpha) + delta)^r - delta^r
        vfloat4 oa, ob;
        oa.x = fpow(fmaf(xa.x, fpow(EPS_C + m0, nalpha), delta), r) - delta_r;
        oa.y = fpow(fmaf(xa.y, fpow(EPS_C + m1, nalpha), delta), r) - delta_r;
        oa.z = fpow(fmaf(xa.z, fpow(EPS_C + m2, nalpha), delta), r) - delta_r;
        oa.w = fpow(fmaf(xa.w, fpow(EPS_C + m3, nalpha), delta), r) - delta_r;
        ob.x = fpow(fmaf(xb.x, fpow(EPS_C + m4, nalpha), delta), r) - delta_r;
        ob.y = fpow(fmaf(xb.y, fpow(EPS_C + m5, nalpha), delta), r) - delta_r;
        ob.z = fpow(fmaf(xb.z, fpow(EPS_C + m6, nalpha), delta), r) - delta_r;
        ob.w = fpow(fmaf(xb.w, fpow(EPS_C + m7, nalpha), delta), r) - delta_r;

        const size_t obase4 = ((size_t)((b * 4 + i) * 128 + f)) * 1024; // /4
        out4[obase4 + 2 * tid]     = oa;
        out4[obase4 + 2 * tid + 1] = ob;
    }
}

extern "C" void kernel_launch(void* const* d_in, const int* in_sizes, int n_in,
                              void* d_out, int out_size, void* d_ws, size_t ws_size,
                              hipStream_t stream) {
    const float* x  = (const float*)d_in[0];
    const float* al = (const float*)d_in[1];
    const float* dl = (const float*)d_in[2];
    const float* rl = (const float*)d_in[3];
    float* out = (float*)d_out;
    const int rows = in_sizes[0] / 4096;   // B*F = 2048
    pcen_kernel<<<rows, 512, 0, stream>>>(x, al, dl, rl, out);
}

// Round 6
// 165.028 us; speedup vs baseline: 1.1271x; 1.0097x over previous
//
#include <hip/hip_runtime.h>

// MRPCEN: multi-rate PCEN.
//   x: (B=16, F=128, T=4096) f32; alpha_log/delta_log/r_log: (F,) f32
//   out: (B, 4, F, T) f32
// m[b,f,0]=x[b,f,0]; m[t]=(1-s)m[t-1]+s x[t]  (4 s-values, compile-time consts)
// out = (x*(EPS+m)^(-alpha) + delta)^r - delta^r
//
// R6: persistent 2-rows-per-block + 1-deep prefetch. Grid 1024, block 512.
// Block handles rows r and r+1024 (f = r&127 identical for both -> params
// loaded once). Row 2's global loads are issued right after the phase-1
// barrier of row 1, so they are in flight during row 1's transcendental
// epilogue + 64 KB store burst -> load latency hidden under the store stream.
// Plain (not nontemporal) vector stores: R4/R5 showed nt stores cost ~20 µs
// (L2 write-back is the fast streaming-write path on gfx950).
// Decoupled scan per row: local 8-step recurrence (zero init) -> wave
// Hillis-Steele scan with decay (1-s)^8 -> cross-wave combine via LDS.
// Initial condition folded by seeding carry with x[0].
//
// NOTE: no <math.h> include — glibc's __MATHCALL declares __exp2f etc. and
// collides with HIP device intrinsics. Use __builtin_amdgcn_* directly.

#define EPS_C 1e-5f

typedef float vfloat4 __attribute__((ext_vector_type(4)));

__device__ __forceinline__ float fexp2(float v) { return __builtin_amdgcn_exp2f(v); }
__device__ __forceinline__ float flog2(float v) { return __builtin_amdgcn_logf(v); }
__device__ __forceinline__ float fpow(float a, float b) { return fexp2(b * flog2(a)); }
__device__ __forceinline__ float fexp(float v) { return fexp2(v * 1.44269504f); }

__global__ __launch_bounds__(512)
void pcen_kernel(const float* __restrict__ x,
                 const float* __restrict__ alpha_log,
                 const float* __restrict__ delta_log,
                 const float* __restrict__ r_log,
                 float* __restrict__ out,
                 int rowstride)               // rows handled: blockIdx.x, blockIdx.x+rowstride
{
    const int tid  = threadIdx.x;         // 0..511
    const int lane = tid & 63;
    const int w    = tid >> 6;            // wave id 0..7
    const int row0 = blockIdx.x;
    const int f    = row0 & 127;          // same for both rows (rowstride % 128 == 0)

    __shared__ float wq[4][8];            // per-s, per-wave inclusive scan tails
    __shared__ float sh_x0;

    // Per-F parameters once (shared by both rows)
    const float al = alpha_log[f], dl = delta_log[f], rl = r_log[f];
    const float nalpha  = -fexp(al);
    const float delta   =  fexp(dl);
    const float r       =  fexp(rl);
    const float delta_r =  fexp(r * dl);  // delta^r = exp(r*log(delta))

    // s-values from module constants (const-folded by the compiler)
    const float Tv[4] = {0.015f, 0.06f, 0.25f, 1.0f};
    float s_arr[4], omn_arr[4];
#pragma unroll
    for (int i = 0; i < 4; ++i) {
        float t  = Tv[i] * 86.1328125f;   // 44100/512
        float t2 = t * t;
        float s  = (__builtin_sqrtf(1.0f + 4.0f * t2) - 1.0f) / (2.0f * t2);
        s_arr[i]   = s;
        omn_arr[i] = 1.0f - s;
    }

    const vfloat4* __restrict__ x4 = (const vfloat4*)x;
    vfloat4* __restrict__ out4 = (vfloat4*)out;

    vfloat4 xa = x4[(size_t)row0 * 1024 + 2 * tid];      // elements 8t..8t+3
    vfloat4 xb = x4[(size_t)row0 * 1024 + 2 * tid + 1];  // elements 8t+4..8t+7

#pragma unroll
    for (int it = 0; it < 2; ++it) {
        const int row = row0 + it * rowstride;
        const int b   = row >> 7;

        if (it) __syncthreads();          // protect wq/sh_x0 (prev iter readers)
        if (tid == 0) sh_x0 = xa.x;

        // Phase 1: per-s local 8-step recurrence + wave scan
        float qxv[4];
#pragma unroll
        for (int i = 0; i < 4; ++i) {
            const float s = s_arr[i], omn = omn_arr[i];
            float p = s * xa.x;
            p = fmaf(omn, p, s * xa.y);
            p = fmaf(omn, p, s * xa.z);
            p = fmaf(omn, p, s * xa.w);
            p = fmaf(omn, p, s * xb.x);
            p = fmaf(omn, p, s * xb.y);
            p = fmaf(omn, p, s * xb.z);
            p = fmaf(omn, p, s * xb.w);
            // wave-level inclusive scan of segment sums, segment decay omn^8
            float q = p;
            float c = omn * omn; c = c * c; c = c * c;   // omn^8
#pragma unroll
            for (int k = 0; k < 6; ++k) {
                int d = 1 << k;
                float tsh = __shfl_up(q, d);
                if (lane >= d) q = fmaf(c, tsh, q);
                c = c * c;
            }
            float qx = __shfl_up(q, 1);   // within-wave exclusive
            if (lane == 0) qx = 0.0f;
            qxv[i] = qx;
            if (lane == 63) wq[i][w] = q;
        }
        __syncthreads();

        // Prefetch next row while the epilogue (trans + stores) runs
        vfloat4 xna, xnb;
        if (it == 0) {
            const size_t nb4 = (size_t)(row0 + rowstride) * 1024;
            xna = x4[nb4 + 2 * tid];
            xnb = x4[nb4 + 2 * tid + 1];
        }

        const float x0 = sh_x0;

#pragma unroll
        for (int i = 0; i < 4; ++i) {
            const float s = s_arr[i], omn = omn_arr[i];
            const float l2omn = flog2(omn);
            const float Dw = fexp2(512.0f * l2omn);      // omn^512 (wave decay)
            // carry entering this wave; seed with M(-1)=x0 so m[0]=x[0] exactly
            float Q = x0;
            for (int v = 0; v < w; ++v) Q = fmaf(Dw, Q, wq[i][v]);
            // carry entering this thread's 8-element segment
            const float dl8 = fexp2((float)(8 * lane) * l2omn); // omn^(8*lane)
            const float E = fmaf(dl8, Q, qxv[i]);
            // replay recurrence from true carry
            float m0 = fmaf(omn, E,  s * xa.x);
            float m1 = fmaf(omn, m0, s * xa.y);
            float m2 = fmaf(omn, m1, s * xa.z);
            float m3 = fmaf(omn, m2, s * xa.w);
            float m4 = fmaf(omn, m3, s * xb.x);
            float m5 = fmaf(omn, m4, s * xb.y);
            float m6 = fmaf(omn, m5, s * xb.z);
            float m7 = fmaf(omn, m6, s * xb.w);
            // pcen = (x*(EPS+m)^(-alpha) + delta)^r - delta^r
            vfloat4 oa, ob;
            oa.x = fpow(fmaf(xa.x, fpow(EPS_C + m0, nalpha), delta), r) - delta_r;
            oa.y = fpow(fmaf(xa.y, fpow(EPS_C + m1, nalpha), delta), r) - delta_r;
            oa.z = fpow(fmaf(xa.z, fpow(EPS_C + m2, nalpha), delta), r) - delta_r;
            oa.w = fpow(fmaf(xa.w, fpow(EPS_C + m3, nalpha), delta), r) - delta_r;
            ob.x = fpow(fmaf(xb.x, fpow(EPS_C + m4, nalpha), delta), r) - delta_r;
            ob.y = fpow(fmaf(xb.y, fpow(EPS_C + m5, nalpha), delta), r) - delta_r;
            ob.z = fpow(fmaf(xb.z, fpow(EPS_C + m6, nalpha), delta), r) - delta_r;
            ob.w = fpow(fmaf(xb.w, fpow(EPS_C + m7, nalpha), delta), r) - delta_r;

            const size_t obase4 = ((size_t)((b * 4 + i) * 128 + f)) * 1024; // /4
            out4[obase4 + 2 * tid]     = oa;
            out4[obase4 + 2 * tid + 1] = ob;
        }

        if (it == 0) { xa = xna; xb = xnb; }
    }
}

extern "C" void kernel_launch(void* const* d_in, const int* in_sizes, int n_in,
                              void* d_out, int out_size, void* d_ws, size_t ws_size,
                              hipStream_t stream) {
    const float* x  = (const float*)d_in[0];
    const float* al = (const float*)d_in[1];
    const float* dl = (const float*)d_in[2];
    const float* rl = (const float*)d_in[3];
    float* out = (float*)d_out;
    const int rows = in_sizes[0] / 4096;   // B*F = 2048
    const int grid = rows / 2;             // 2 rows per block, stride = grid
    pcen_kernel<<<grid, 512, 0, stream>>>(x, al, dl, rl, out, grid);
}